// Round 4
// baseline (215.172 us; speedup 1.0000x reference)
//
#include <hip/hip_runtime.h>

#define BATCHN 131072
#define M_TILE 64
#define NTHREADS 1024         // 16 waves: wave = nt + 8*mt
#define HPITCH 280            // halves/row = 560B; >=272 so bias chunk [256..271] is in-row
#define W2P_OFF 4096          // w1p = 8 chunks x 512 halves
#define W3P_OFF 73728         // w2p = 8*17 chunks x 512
#define NET_STRIDE 77824      // + w3p = 8 chunks x 512
#define PACK_TOTAL (4 * NET_STRIDE)

typedef _Float16 hv8 __attribute__((ext_vector_type(8)));
typedef _Float16 hv4 __attribute__((ext_vector_type(4)));
typedef __fp16  fp16x2 __attribute__((ext_vector_type(2)));
typedef float f32x16 __attribute__((ext_vector_type(16)));
typedef float f32x4  __attribute__((ext_vector_type(4)));

struct __align__(16) SMEM {
    _Float16 xin[M_TILE][16];     // cols0..7 input, col8 = 1.0 (bias), 9..15 = 0
    _Float16 Ha[M_TILE][HPITCH];  // [m][n]; cols 256..271 = [1,0,...] persistent bias pad
    _Float16 Hb[M_TILE][HPITCH];
    float s_tile[M_TILE][8];
    float t_tile[M_TILE][8];
    float ldet[M_TILE];
};                                // 78080 B -> 2 blocks/CU (x16 waves = 8 waves/SIMD)

// ---------------- weight pre-pack (unchanged layout from round 3) ----------------
__global__ __launch_bounds__(256) void pack_weights(
    const float* __restrict__ s1w1, const float* __restrict__ s1b1, const float* __restrict__ s1w2, const float* __restrict__ s1b2, const float* __restrict__ s1w3,
    const float* __restrict__ t1w1, const float* __restrict__ t1b1, const float* __restrict__ t1w2, const float* __restrict__ t1b2, const float* __restrict__ t1w3,
    const float* __restrict__ s2w1, const float* __restrict__ s2b1, const float* __restrict__ s2w2, const float* __restrict__ s2b2, const float* __restrict__ s2w3,
    const float* __restrict__ t2w1, const float* __restrict__ t2b1, const float* __restrict__ t2w2, const float* __restrict__ t2b2, const float* __restrict__ t2w3,
    _Float16* __restrict__ wp)
{
    int tid = blockIdx.x * 256 + threadIdx.x;
    if (tid >= PACK_TOTAL) return;
    int net = tid / NET_STRIDE;
    int rem = tid - net * NET_STRIDE;
    const float* w1 = (net == 0) ? s1w1 : (net == 1) ? t1w1 : (net == 2) ? s2w1 : t2w1;
    const float* b1 = (net == 0) ? s1b1 : (net == 1) ? t1b1 : (net == 2) ? s2b1 : t2b1;
    const float* w2 = (net == 0) ? s1w2 : (net == 1) ? t1w2 : (net == 2) ? s2w2 : t2w2;
    const float* b2 = (net == 0) ? s1b2 : (net == 1) ? t1b2 : (net == 2) ? s2b2 : t2b2;
    const float* w3 = (net == 0) ? s1w3 : (net == 1) ? t1w3 : (net == 2) ? s2w3 : t2w3;
    float val;
    if (rem < W2P_OFF) {
        int nt = rem >> 9;
        int l  = (rem >> 3) & 63, j = rem & 7;
        int n  = nt * 32 + (l & 31);
        int k  = ((l >> 5) << 3) + j;
        val = (k < 8) ? w1[n * 8 + k] : (k == 8 ? b1[n] : 0.0f);
    } else if (rem < W3P_OFF) {
        int r = rem - W2P_OFF;
        int chunk = r >> 9;
        int nt = chunk / 17, ks = chunk - nt * 17;
        int l = (r >> 3) & 63, j = r & 7;
        int n = nt * 32 + (l & 31);
        int kk = ((l >> 5) << 3) + j;
        val = (ks < 16) ? w2[n * 256 + ks * 16 + kk] : (kk == 0 ? b2[n] : 0.0f);
    } else {
        int r = rem - W3P_OFF;
        int ks = r >> 9;
        int l = (r >> 3) & 63, j = r & 7;
        int n = l & 15;
        int k = ks * 32 + ((l >> 4) & 3) * 8 + j;
        val = (n < 8) ? w3[n * 256 + k] : 0.0f;
    }
    wp[tid] = (_Float16)val;
}

#define MFMA32(A,B,C) __builtin_amdgcn_mfma_f32_32x32x16_f16((A),(B),(C),0,0,0)

// relu + f16-pack + 4x ds_write_b64 at immediate offsets.  dst = &H[row][nt*32 + 4*hi]
__device__ __forceinline__ void epi4(_Float16* __restrict__ dst, const f32x16& acc)
{
    #pragma unroll
    for (int q = 0; q < 4; ++q) {
        union { hv4 h4; fp16x2 h2[2]; } u;
        u.h2[0] = __builtin_amdgcn_cvt_pkrtz(fmaxf(acc[4*q+0], 0.f), fmaxf(acc[4*q+1], 0.f));
        u.h2[1] = __builtin_amdgcn_cvt_pkrtz(fmaxf(acc[4*q+2], 0.f), fmaxf(acc[4*q+3], 0.f));
        *(hv4*)(dst + 8 * q) = u.h4;   // n_local = 8q + 4hi + i
    }
}

// L1: D[n][m] = W1(+b1) @ [x|1]^T, relu -> Ha.  1 MFMA per wave.
__device__ __forceinline__ void layer1(const _Float16* __restrict__ wp, SMEM& sm,
                                       int nt, int mt, int lane, int l31, int hi)
{
    hv8 a = *(const hv8*)(wp + nt * 512 + lane * 8);
    hv8 b = *(const hv8*)(&sm.xin[mt * 32 + l31][hi * 8]);
    f32x16 z = {};
    f32x16 acc = MFMA32(a, b, z);
    epi4(&sm.Ha[mt * 32 + l31][nt * 32 + 4 * hi], acc);
}

// L2: K=256 (+bias chunk ks=16 hitting Ha cols 256..271), relu -> Hb.  17 MFMA per wave.
__device__ __forceinline__ void layer2(const _Float16* __restrict__ wp, SMEM& sm,
                                       int nt, int mt, int lane, int l31, int hi)
{
    const _Float16* __restrict__ w2 = wp + W2P_OFF + nt * (17 * 512);
    const _Float16* __restrict__ bb = &sm.Ha[mt * 32 + l31][hi * 8];
    f32x16 acc = {};
    #pragma unroll
    for (int ks = 0; ks < 17; ++ks) {
        hv8 a = *(const hv8*)(w2 + ks * 512 + lane * 8);
        hv8 b = *(const hv8*)(bb + ks * 16);        // uniform imm offset: 32B * ks
        acc = MFMA32(a, b, acc);
    }
    epi4(&sm.Hb[mt * 32 + l31][nt * 32 + 4 * hi], acc);
}

// L3: 16x16x32, waves 0..3 (rows wave*16..+15), K=256 from Hb -> stile (+b3, opt tanh)
template <bool IS_S>
__device__ __forceinline__ void layer3(const _Float16* __restrict__ wp, const float* __restrict__ b3,
                                       SMEM& sm, float (*__restrict__ stile)[8],
                                       int wave, int lane)
{
    if (wave >= 4) return;
    const _Float16* __restrict__ w3 = wp + W3P_OFF;
    const int l15 = lane & 15, q = lane >> 4;
    const int m = wave * 16 + l15;
    const _Float16* __restrict__ bb = &sm.Hb[m][q * 8];
    f32x4 acc = {};
    #pragma unroll
    for (int ks = 0; ks < 8; ++ks) {
        hv8 a = *(const hv8*)(w3 + ks * 512 + lane * 8);
        hv8 b = *(const hv8*)(bb + ks * 32);        // uniform imm offset: 64B * ks
        acc = __builtin_amdgcn_mfma_f32_16x16x32_f16(a, b, acc, 0, 0, 0);
    }
    if (q < 2) {                                    // n = q*4 + r, valid n < 8
        float4 bv = *(const float4*)(b3 + q * 4);
        float o0 = acc[0] + bv.x, o1 = acc[1] + bv.y, o2 = acc[2] + bv.z, o3 = acc[3] + bv.w;
        if (IS_S) { o0 = tanhf(o0); o1 = tanhf(o1); o2 = tanhf(o2); o3 = tanhf(o3); }
        *(float4*)&stile[m][q * 4] = make_float4(o0, o1, o2, o3);
    }
}

// one coupling stage: s-net and t-net, with L1(t) merged into the L3(s) phase
__device__ __forceinline__ void stage(const _Float16* __restrict__ wpS, const float* __restrict__ b3S,
                                      const _Float16* __restrict__ wpT, const float* __restrict__ b3T,
                                      SMEM& sm,
                                      int wave, int nt, int mt, int lane, int l31, int hi)
{
    layer1(wpS, sm, nt, mt, lane, l31, hi);
    __syncthreads();
    layer2(wpS, sm, nt, mt, lane, l31, hi);
    __syncthreads();
    layer1(wpT, sm, nt, mt, lane, l31, hi);          // writes Ha (free: no reader now)
    layer3<true >(wpS, b3S, sm, sm.s_tile, wave, lane);  // reads Hb
    __syncthreads();
    layer2(wpT, sm, nt, mt, lane, l31, hi);
    __syncthreads();
    layer3<false>(wpT, b3T, sm, sm.t_tile, wave, lane);
    __syncthreads();
}

__global__ __launch_bounds__(NTHREADS, 8) void coupling_kernel(
    const float* __restrict__ x, const _Float16* __restrict__ wp,
    const float* __restrict__ s1b3, const float* __restrict__ t1b3,
    const float* __restrict__ s2b3, const float* __restrict__ t2b3,
    float* __restrict__ out)
{
    __shared__ SMEM sm;
    const int tid  = threadIdx.x;
    const int wave = tid >> 6, lane = tid & 63;
    const int l31  = lane & 31, hi = lane >> 5;
    const int nt   = wave & 7, mt = wave >> 3;
    const long row0 = (long)blockIdx.x * M_TILE;

    // xin <- [x2, 1, 0...]  (1024 elems, one per thread)
    {
        int row = tid >> 4, c = tid & 15;
        float v = (c < 8) ? x[(row0 + row) * 16 + 8 + c] : (c == 8 ? 1.0f : 0.0f);
        sm.xin[row][c] = (_Float16)v;
        sm.Ha[row][256 + c] = (c == 0) ? (_Float16)1.0f : (_Float16)0.0f;  // persistent bias pad
    }
    __syncthreads();

    stage(wp + 0 * NET_STRIDE, s1b3, wp + 1 * NET_STRIDE, t1b3, sm, wave, nt, mt, lane, l31, hi);

    // y1 = x1 * exp(s2) + t2 ; ldet partial ; xin <- y1 (col 8 stays 1.0)
    if (tid < M_TILE * 8) {
        int row = tid >> 3, c = tid & 7;
        float s = sm.s_tile[row][c];
        float t = sm.t_tile[row][c];
        float x1 = x[(row0 + row) * 16 + c];
        float y = x1 * expf(s) + t;
        out[(row0 + row) * 16 + c] = y;
        sm.xin[row][c] = (_Float16)y;
    }
    if (tid < M_TILE) {
        float a = 0.f;
        #pragma unroll
        for (int c = 0; c < 8; ++c) a += sm.s_tile[tid][c];
        sm.ldet[tid] = a;
    }
    __syncthreads();

    stage(wp + 2 * NET_STRIDE, s2b3, wp + 3 * NET_STRIDE, t2b3, sm, wave, nt, mt, lane, l31, hi);

    // y2 = x2 * exp(s1) + t1 ; log_det
    if (tid < M_TILE * 8) {
        int row = tid >> 3, c = tid & 7;
        float s = sm.s_tile[row][c];
        float t = sm.t_tile[row][c];
        float x2 = x[(row0 + row) * 16 + 8 + c];
        out[(row0 + row) * 16 + 8 + c] = x2 * expf(s) + t;
    }
    if (tid < M_TILE) {
        float a = sm.ldet[tid];
        #pragma unroll
        for (int c = 0; c < 8; ++c) a += sm.s_tile[tid][c];
        out[(long)BATCHN * 16 + row0 + tid] = a;
    }
}

extern "C" void kernel_launch(void* const* d_in, const int* in_sizes, int n_in,
                              void* d_out, int out_size, void* d_ws, size_t ws_size,
                              hipStream_t stream)
{
    const float* x = (const float*)d_in[0];
    const float* s1w1 = (const float*)d_in[1];  const float* s1b1 = (const float*)d_in[2];
    const float* s1w2 = (const float*)d_in[3];  const float* s1b2 = (const float*)d_in[4];
    const float* s1w3 = (const float*)d_in[5];  const float* s1b3 = (const float*)d_in[6];
    const float* t1w1 = (const float*)d_in[7];  const float* t1b1 = (const float*)d_in[8];
    const float* t1w2 = (const float*)d_in[9];  const float* t1b2 = (const float*)d_in[10];
    const float* t1w3 = (const float*)d_in[11]; const float* t1b3 = (const float*)d_in[12];
    const float* s2w1 = (const float*)d_in[13]; const float* s2b1 = (const float*)d_in[14];
    const float* s2w2 = (const float*)d_in[15]; const float* s2b2 = (const float*)d_in[16];
    const float* s2w3 = (const float*)d_in[17]; const float* s2b3 = (const float*)d_in[18];
    const float* t2w1 = (const float*)d_in[19]; const float* t2b1 = (const float*)d_in[20];
    const float* t2w2 = (const float*)d_in[21]; const float* t2b2 = (const float*)d_in[22];
    const float* t2w3 = (const float*)d_in[23]; const float* t2b3 = (const float*)d_in[24];

    _Float16* wp = (_Float16*)d_ws;   // 622592 B used; repacked every launch

    pack_weights<<<(PACK_TOTAL + 255) / 256, 256, 0, stream>>>(
        s1w1, s1b1, s1w2, s1b2, s1w3,
        t1w1, t1b1, t1w2, t1b2, t1w3,
        s2w1, s2b1, s2w2, s2b2, s2w3,
        t2w1, t2b1, t2w2, t2b2, t2w3, wp);

    coupling_kernel<<<BATCHN / M_TILE, NTHREADS, 0, stream>>>(
        x, wp, s1b3, t1b3, s2b3, t2b3, (float*)d_out);
}

// Round 6
// 196.055 us; speedup vs baseline: 1.0975x; 1.0975x over previous
//
#include <hip/hip_runtime.h>

#define BATCHN 131072
#define M_TILE 128
#define NTHREADS 1024         // 16 waves: wave = mt + 2*nt  (pair waves share an nt weight slice)
#define HPITCH 280            // halves/row = 560B; bias chunk cols 256..271 in-row; 560/4=140≡12 mod 32 -> conflict-light
#define W2P_OFF 4096          // w1p = 8 chunks x 512 halves
#define W3P_OFF 73728         // w2p = 8*17 chunks x 512
#define NET_STRIDE 77824      // + w3p = 8 chunks x 512
#define PACK_TOTAL (4 * NET_STRIDE)

typedef _Float16 hv8 __attribute__((ext_vector_type(8)));
typedef _Float16 hv4 __attribute__((ext_vector_type(4)));
typedef __fp16  fp16x2 __attribute__((ext_vector_type(2)));
typedef float f32x16 __attribute__((ext_vector_type(16)));
typedef float f32x4  __attribute__((ext_vector_type(4)));

struct __align__(16) SMEM {
    _Float16 xin[M_TILE][16];     // cols0..7 input, col8 = 1.0 (bias), 9..15 = 0
    _Float16 Ha[M_TILE][HPITCH];  // [m][n]; cols 256..271 = [1,0,...] persistent bias pad
    _Float16 Hb[M_TILE][HPITCH];
    float s_tile[M_TILE][8];
    float t_tile[M_TILE][8];
    float ldet[M_TILE];
};                                // 156160 B -> 1 block/CU, 16 waves = 4 waves/SIMD

// ---------------- weight pre-pack (layout unchanged from round 3/4) ----------------
__global__ __launch_bounds__(256) void pack_weights(
    const float* __restrict__ s1w1, const float* __restrict__ s1b1, const float* __restrict__ s1w2, const float* __restrict__ s1b2, const float* __restrict__ s1w3,
    const float* __restrict__ t1w1, const float* __restrict__ t1b1, const float* __restrict__ t1w2, const float* __restrict__ t1b2, const float* __restrict__ t1w3,
    const float* __restrict__ s2w1, const float* __restrict__ s2b1, const float* __restrict__ s2w2, const float* __restrict__ s2b2, const float* __restrict__ s2w3,
    const float* __restrict__ t2w1, const float* __restrict__ t2b1, const float* __restrict__ t2w2, const float* __restrict__ t2b2, const float* __restrict__ t2w3,
    _Float16* __restrict__ wp)
{
    int tid = blockIdx.x * 256 + threadIdx.x;
    if (tid >= PACK_TOTAL) return;
    int net = tid / NET_STRIDE;
    int rem = tid - net * NET_STRIDE;
    const float* w1 = (net == 0) ? s1w1 : (net == 1) ? t1w1 : (net == 2) ? s2w1 : t2w1;
    const float* b1 = (net == 0) ? s1b1 : (net == 1) ? t1b1 : (net == 2) ? s2b1 : t2b1;
    const float* w2 = (net == 0) ? s1w2 : (net == 1) ? t1w2 : (net == 2) ? s2w2 : t2w2;
    const float* b2 = (net == 0) ? s1b2 : (net == 1) ? t1b2 : (net == 2) ? s2b2 : t2b2;
    const float* w3 = (net == 0) ? s1w3 : (net == 1) ? t1w3 : (net == 2) ? s2w3 : t2w3;
    float val;
    if (rem < W2P_OFF) {
        int nt = rem >> 9;
        int l  = (rem >> 3) & 63, j = rem & 7;
        int n  = nt * 32 + (l & 31);
        int k  = ((l >> 5) << 3) + j;
        val = (k < 8) ? w1[n * 8 + k] : (k == 8 ? b1[n] : 0.0f);
    } else if (rem < W3P_OFF) {
        int r = rem - W2P_OFF;
        int chunk = r >> 9;
        int nt = chunk / 17, ks = chunk - nt * 17;
        int l = (r >> 3) & 63, j = r & 7;
        int n = nt * 32 + (l & 31);
        int kk = ((l >> 5) << 3) + j;
        val = (ks < 16) ? w2[n * 256 + ks * 16 + kk] : (kk == 0 ? b2[n] : 0.0f);
    } else {
        int r = rem - W3P_OFF;
        int ks = r >> 9;
        int l = (r >> 3) & 63, j = r & 7;
        int n = l & 15;
        int k = ks * 32 + ((l >> 4) & 3) * 8 + j;
        val = (n < 8) ? w3[n * 256 + k] : 0.0f;
    }
    wp[tid] = (_Float16)val;
}

#define MFMA32(A,B,C) __builtin_amdgcn_mfma_f32_32x32x16_f16((A),(B),(C),0,0,0)

// relu + f16-pack + 4x ds_write_b64 at immediate offsets.  dst = &H[row][nt*32 + 4*hi]
__device__ __forceinline__ void epi4(_Float16* __restrict__ dst, const f32x16& acc)
{
    #pragma unroll
    for (int q = 0; q < 4; ++q) {
        union { hv4 h4; fp16x2 h2[2]; } u;
        u.h2[0] = __builtin_amdgcn_cvt_pkrtz(fmaxf(acc[4*q+0], 0.f), fmaxf(acc[4*q+1], 0.f));
        u.h2[1] = __builtin_amdgcn_cvt_pkrtz(fmaxf(acc[4*q+2], 0.f), fmaxf(acc[4*q+3], 0.f));
        *(hv4*)(dst + 8 * q) = u.h4;   // n_local = 8q + 4hi + i
    }
}

// L1: D[n][m] = W1(+b1) @ [x|1]^T, relu -> Ha.  2 MFMA per wave (2 m-subtiles).
__device__ __forceinline__ void layer1(const _Float16* __restrict__ wp, SMEM& sm,
                                       int nt, int mt, int lane, int l31, int hi)
{
    hv8 a  = *(const hv8*)(wp + nt * 512 + lane * 8);
    hv8 b0 = *(const hv8*)(&sm.xin[mt * 64 + l31][hi * 8]);
    hv8 b1 = *(const hv8*)(&sm.xin[mt * 64 + 32 + l31][hi * 8]);
    f32x16 z = {};
    f32x16 acc0 = MFMA32(a, b0, z);
    f32x16 acc1 = MFMA32(a, b1, z);
    epi4(&sm.Ha[mt * 64 + l31][nt * 32 + 4 * hi], acc0);
    epi4(&sm.Ha[mt * 64 + 32 + l31][nt * 32 + 4 * hi], acc1);
}

// L2: K=256 (+bias chunk ks=16 -> Ha cols 256..271), relu -> Hb.
// Full 17-chunk register preload (68 VGPR) so the global stream overlaps the 34 MFMAs.
__device__ __forceinline__ void layer2(const _Float16* __restrict__ wp, SMEM& sm,
                                       int nt, int mt, int lane, int l31, int hi)
{
    const _Float16* __restrict__ w2 = wp + W2P_OFF + nt * (17 * 512);
    hv8 w[17];
    #pragma unroll
    for (int ks = 0; ks < 17; ++ks) w[ks] = *(const hv8*)(w2 + ks * 512 + lane * 8);
    const _Float16* __restrict__ bb0 = &sm.Ha[mt * 64 + l31][hi * 8];
    const _Float16* __restrict__ bb1 = &sm.Ha[mt * 64 + 32 + l31][hi * 8];
    f32x16 acc0 = {}, acc1 = {};
    #pragma unroll
    for (int ks = 0; ks < 17; ++ks) {
        hv8 b0 = *(const hv8*)(bb0 + ks * 16);      // uniform imm offset: 32B * ks
        hv8 b1 = *(const hv8*)(bb1 + ks * 16);
        acc0 = MFMA32(w[ks], b0, acc0);
        acc1 = MFMA32(w[ks], b1, acc1);
    }
    epi4(&sm.Hb[mt * 64 + l31][nt * 32 + 4 * hi], acc0);
    epi4(&sm.Hb[mt * 64 + 32 + l31][nt * 32 + 4 * hi], acc1);
}

// L3: 16x16x32, waves 0..7 (one 16-row m-tile each), K=256 from Hb -> stile (+b3, opt tanh)
template <bool IS_S>
__device__ __forceinline__ void layer3(const _Float16* __restrict__ wp, const float* __restrict__ b3,
                                       SMEM& sm, float (*__restrict__ stile)[8],
                                       int wave, int lane)
{
    if (wave >= 8) return;
    const _Float16* __restrict__ w3 = wp + W3P_OFF;
    const int l15 = lane & 15, q = lane >> 4;
    const int m = wave * 16 + l15;
    hv8 w[8];
    #pragma unroll
    for (int ks = 0; ks < 8; ++ks) w[ks] = *(const hv8*)(w3 + ks * 512 + lane * 8);
    const _Float16* __restrict__ bb = &sm.Hb[m][q * 8];
    f32x4 acc = {};
    #pragma unroll
    for (int ks = 0; ks < 8; ++ks)
        acc = __builtin_amdgcn_mfma_f32_16x16x32_f16(w[ks], *(const hv8*)(bb + ks * 32), acc, 0, 0, 0);
    if (q < 2) {                                    // n = q*4 + r, valid n < 8
        float4 bv = *(const float4*)(b3 + q * 4);
        float o0 = acc[0] + bv.x, o1 = acc[1] + bv.y, o2 = acc[2] + bv.z, o3 = acc[3] + bv.w;
        if (IS_S) { o0 = tanhf(o0); o1 = tanhf(o1); o2 = tanhf(o2); o3 = tanhf(o3); }
        *(float4*)&stile[m][q * 4] = make_float4(o0, o1, o2, o3);
    }
}

// one coupling stage: s-net and t-net, with L1(t) merged into the L3(s) phase
__device__ __forceinline__ void stage(const _Float16* __restrict__ wpS, const float* __restrict__ b3S,
                                      const _Float16* __restrict__ wpT, const float* __restrict__ b3T,
                                      SMEM& sm,
                                      int wave, int nt, int mt, int lane, int l31, int hi)
{
    layer1(wpS, sm, nt, mt, lane, l31, hi);
    __syncthreads();
    layer2(wpS, sm, nt, mt, lane, l31, hi);
    __syncthreads();
    layer1(wpT, sm, nt, mt, lane, l31, hi);              // writes Ha (L2s already read it)
    layer3<true >(wpS, b3S, sm, sm.s_tile, wave, lane);  // reads Hb
    __syncthreads();
    layer2(wpT, sm, nt, mt, lane, l31, hi);
    __syncthreads();
    layer3<false>(wpT, b3T, sm, sm.t_tile, wave, lane);
    __syncthreads();
}

__global__ __launch_bounds__(NTHREADS, 4) void coupling_kernel(
    const float* __restrict__ x, const _Float16* __restrict__ wp,
    const float* __restrict__ s1b3, const float* __restrict__ t1b3,
    const float* __restrict__ s2b3, const float* __restrict__ t2b3,
    float* __restrict__ out)
{
    __shared__ SMEM sm;
    const int tid  = threadIdx.x;
    const int wave = tid >> 6, lane = tid & 63;
    const int l31  = lane & 31, hi = lane >> 5;
    const int mt   = wave & 1, nt = wave >> 1;   // pair waves (2nt, 2nt+1) share weight slice nt
    const long row0 = (long)blockIdx.x * M_TILE;

    // xin <- [x2, 1, 0...]; Ha bias pad cols 256..271 <- [1,0...] (persists for all 4 MLPs)
    #pragma unroll
    for (int e = tid; e < M_TILE * 16; e += NTHREADS) {
        int row = e >> 4, c = e & 15;
        float v = (c < 8) ? x[(row0 + row) * 16 + 8 + c] : (c == 8 ? 1.0f : 0.0f);
        sm.xin[row][c] = (_Float16)v;
        sm.Ha[row][256 + c] = (c == 0) ? (_Float16)1.0f : (_Float16)0.0f;
    }
    __syncthreads();

    stage(wp + 0 * NET_STRIDE, s1b3, wp + 1 * NET_STRIDE, t1b3, sm, wave, nt, mt, lane, l31, hi);

    // y1 = x1 * exp(s2) + t2 ; ldet partial ; xin <- y1 (col 8 stays 1.0)   [1024 thr = 128x8]
    {
        int row = tid >> 3, c = tid & 7;
        float s = sm.s_tile[row][c];
        float t = sm.t_tile[row][c];
        float x1 = x[(row0 + row) * 16 + c];
        float y = x1 * expf(s) + t;
        out[(row0 + row) * 16 + c] = y;
        sm.xin[row][c] = (_Float16)y;
    }
    if (tid < M_TILE) {
        float a = 0.f;
        #pragma unroll
        for (int c = 0; c < 8; ++c) a += sm.s_tile[tid][c];
        sm.ldet[tid] = a;
    }
    __syncthreads();

    stage(wp + 2 * NET_STRIDE, s2b3, wp + 3 * NET_STRIDE, t2b3, sm, wave, nt, mt, lane, l31, hi);

    // y2 = x2 * exp(s1) + t1 ; log_det
    {
        int row = tid >> 3, c = tid & 7;
        float s = sm.s_tile[row][c];
        float t = sm.t_tile[row][c];
        float x2 = x[(row0 + row) * 16 + 8 + c];
        out[(row0 + row) * 16 + 8 + c] = x2 * expf(s) + t;
    }
    if (tid < M_TILE) {
        float a = sm.ldet[tid];
        #pragma unroll
        for (int c = 0; c < 8; ++c) a += sm.s_tile[tid][c];
        out[(long)BATCHN * 16 + row0 + tid] = a;
    }
}

extern "C" void kernel_launch(void* const* d_in, const int* in_sizes, int n_in,
                              void* d_out, int out_size, void* d_ws, size_t ws_size,
                              hipStream_t stream)
{
    const float* x = (const float*)d_in[0];
    const float* s1w1 = (const float*)d_in[1];  const float* s1b1 = (const float*)d_in[2];
    const float* s1w2 = (const float*)d_in[3];  const float* s1b2 = (const float*)d_in[4];
    const float* s1w3 = (const float*)d_in[5];  const float* s1b3 = (const float*)d_in[6];
    const float* t1w1 = (const float*)d_in[7];  const float* t1b1 = (const float*)d_in[8];
    const float* t1w2 = (const float*)d_in[9];  const float* t1b2 = (const float*)d_in[10];
    const float* t1w3 = (const float*)d_in[11]; const float* t1b3 = (const float*)d_in[12];
    const float* s2w1 = (const float*)d_in[13]; const float* s2b1 = (const float*)d_in[14];
    const float* s2w2 = (const float*)d_in[15]; const float* s2b2 = (const float*)d_in[16];
    const float* s2w3 = (const float*)d_in[17]; const float* s2b3 = (const float*)d_in[18];
    const float* t2w1 = (const float*)d_in[19]; const float* t2b1 = (const float*)d_in[20];
    const float* t2w2 = (const float*)d_in[21]; const float* t2b2 = (const float*)d_in[22];
    const float* t2w3 = (const float*)d_in[23]; const float* t2b3 = (const float*)d_in[24];

    _Float16* wp = (_Float16*)d_ws;   // 622592 B used; repacked every launch

    pack_weights<<<(PACK_TOTAL + 255) / 256, 256, 0, stream>>>(
        s1w1, s1b1, s1w2, s1b2, s1w3,
        t1w1, t1b1, t1w2, t1b2, t1w3,
        s2w1, s2b1, s2w2, s2b2, s2w3,
        t2w1, t2b1, t2w2, t2b2, t2w3, wp);

    coupling_kernel<<<BATCHN / M_TILE, NTHREADS, 0, stream>>>(
        x, wp, s1b3, t1b3, s2b3, t2b3, (float*)d_out);
}